// Round 6
// baseline (73.928 us; speedup 1.0000x reference)
//
#include <hip/hip_runtime.h>
#include <math.h>

#define NHEAD 8
#define NPT 4
#define HDIM 32
#define IMG 64      // H = W = 64
#define CDIM 256
#define NQ 4096
#define BATCH 8
#define MTOT (BATCH * NQ)   // 32768

typedef __attribute__((ext_vector_type(8))) short bf16x8;
typedef __attribute__((ext_vector_type(4))) float f32x4;

__device__ __forceinline__ unsigned short f2b(float f) {
    union { float f; unsigned u; } v; v.f = f;
    unsigned r = (v.u + 0x7FFFu + ((v.u >> 16) & 1u)) >> 16;
    return (unsigned short)r;
}
__device__ __forceinline__ float b2f(unsigned short u) {
    union { unsigned u; float f; } v; v.u = ((unsigned)u) << 16;
    return v.f;
}

// XOR swizzle (ushort units): read side. Write side uses linear LDS +
// pre-swizzled global source (chunk' = chunk ^ (row&7)) for global_load_lds.
#define SWZ(row, col) ((col) ^ (((row) & 7) << 3))

// Async global->LDS, 16B per lane; dest = wave-uniform base + lane*16.
__device__ __forceinline__ void gload16(const void* src, void* ldsbase) {
    __builtin_amdgcn_global_load_lds(
        (const __attribute__((address_space(1))) void*)src,
        (__attribute__((address_space(3))) void*)ldsbase, 16, 0, 0);
}

// XCD pinning: batch = blockIdx.x & 7 -> XCD (blockIdx % 8) round-robin.
// Each XCD owns one batch's projv/lin/sampled slice -> L2-resident.

// ---------------------------------------------------------------------------
// Weight prep.
// ---------------------------------------------------------------------------
__global__ __launch_bounds__(256)
void cvt_weights_kernel(const float* __restrict__ Wv, const float* __restrict__ Wo,
                        const float* __restrict__ Woff, const float* __restrict__ Wattn,
                        const float* __restrict__ boff, const float* __restrict__ battn,
                        unsigned short* __restrict__ Wv_t, unsigned short* __restrict__ Wo_t,
                        unsigned short* __restrict__ Wl_h, unsigned short* __restrict__ Wl_l,
                        float* __restrict__ bias_lin)
{
    int tid = blockIdx.x * 256 + threadIdx.x;   // 0 .. 65535
    int n = tid & 255, k = tid >> 8;
    Wv_t[n * 256 + k] = f2b(Wv[k * 256 + n]);
    Wo_t[n * 256 + k] = f2b(Wo[k * 256 + n]);
    if (tid < 128 * 256) {
        int nn = tid >> 8;
        int kk = tid & 255;
        float v = (nn < 64) ? Woff[kk * 64 + nn]
                : (nn < 96) ? Wattn[kk * 32 + (nn - 64)] : 0.f;
        unsigned short hi = f2b(v);
        unsigned short lo = f2b(v - b2f(hi));
        Wl_h[nn * 256 + kk] = hi;
        Wl_l[nn * 256 + kk] = lo;
    }
    if (tid < 128)
        bias_lin[tid] = (tid < 64) ? boff[tid] : (tid < 96) ? battn[tid - 64] : 0.f;
}

// ---------------------------------------------------------------------------
// Split-precision MFMA GEMM for offset/attn logits (XCD-pinned rows).
// B (Wl_h/Wl_l) staged via global_load_lds; A (query f32->hi/lo) reg-staged.
// ---------------------------------------------------------------------------
__global__ __launch_bounds__(256)
void lin_gemm_kernel(const float* __restrict__ Q,
                     const unsigned short* __restrict__ Wl_h,
                     const unsigned short* __restrict__ Wl_l,
                     const float* __restrict__ bias,
                     float* __restrict__ lin)
{
    __shared__ unsigned short Ah[128][64], Al[128][64];
    __shared__ unsigned short Bh[128][64], Bl[128][64];

    const int tid  = threadIdx.x;
    const int lane = tid & 63;
    const int wid  = tid >> 6;
    const int gm = ((blockIdx.x & 7) << 12) + ((blockIdx.x >> 3) << 7);
    const int wr = (wid >> 1) * 64;
    const int wc = (wid & 1) * 64;
    const int l15 = lane & 15;
    const int lk  = (lane >> 4) * 8;
    const int rl  = lane >> 3;                 // 0..7 (row within 8-row stripe)
    const int ch  = (lane & 7) ^ (rl & 7);     // pre-swizzled source chunk

    f32x4 acc[4][4];
    #pragma unroll
    for (int m = 0; m < 4; ++m)
        #pragma unroll
        for (int n = 0; n < 4; ++n)
            #pragma unroll
            for (int r = 0; r < 4; ++r) acc[m][n][r] = 0.f;

    for (int k0 = 0; k0 < 256; k0 += 64) {
        // async B staging (linear LDS, pre-swizzled source)
        #pragma unroll
        for (int it = 0; it < 4; ++it) {
            const int br = it * 32 + wid * 8;
            gload16(&Wl_h[(size_t)(br + rl) * 256 + k0 + ch * 8], &Bh[br][0]);
            gload16(&Wl_l[(size_t)(br + rl) * 256 + k0 + ch * 8], &Bl[br][0]);
        }
        // reg-staged A hi/lo split
        #pragma unroll
        for (int it = 0; it < 4; ++it) {
            const int chunk = it * 256 + tid;
            const int row = chunk >> 3;
            const int kc  = (chunk & 7) << 3;
            const float4* src = (const float4*)&Q[(size_t)(gm + row) * 256 + k0 + kc];
            const float4 a = src[0], b = src[1];
            float f[8] = {a.x, a.y, a.z, a.w, b.x, b.y, b.z, b.w};
            unsigned short h[8], l[8];
            #pragma unroll
            for (int j = 0; j < 8; ++j) {
                h[j] = f2b(f[j]);
                l[j] = f2b(f[j] - b2f(h[j]));
            }
            const int sc = SWZ(row, kc);
            *(uint4*)&Ah[row][sc] = *(const uint4*)h;
            *(uint4*)&Al[row][sc] = *(const uint4*)l;
        }
        __syncthreads();

        #pragma unroll
        for (int kk = 0; kk < 64; kk += 32) {
            bf16x8 ah[4], al[4];
            #pragma unroll
            for (int m = 0; m < 4; ++m) {
                const int r = wr + m * 16 + l15;
                const int c = SWZ(r, kk + lk);
                ah[m] = *(const bf16x8*)&Ah[r][c];
                al[m] = *(const bf16x8*)&Al[r][c];
            }
            if (wc == 0) {
                bf16x8 bh[4], bl[4];
                #pragma unroll
                for (int n = 0; n < 4; ++n) {
                    const int r = n * 16 + l15;
                    const int c = SWZ(r, kk + lk);
                    bh[n] = *(const bf16x8*)&Bh[r][c];
                    bl[n] = *(const bf16x8*)&Bl[r][c];
                }
                #pragma unroll
                for (int m = 0; m < 4; ++m)
                    #pragma unroll
                    for (int n = 0; n < 4; ++n) {
                        acc[m][n] = __builtin_amdgcn_mfma_f32_16x16x32_bf16(ah[m], bh[n], acc[m][n], 0, 0, 0);
                        acc[m][n] = __builtin_amdgcn_mfma_f32_16x16x32_bf16(ah[m], bl[n], acc[m][n], 0, 0, 0);
                        acc[m][n] = __builtin_amdgcn_mfma_f32_16x16x32_bf16(al[m], bh[n], acc[m][n], 0, 0, 0);
                    }
            } else {
                bf16x8 bh[2], bl[2];
                #pragma unroll
                for (int n = 0; n < 2; ++n) {
                    const int r = 64 + n * 16 + l15;
                    const int c = SWZ(r, kk + lk);
                    bh[n] = *(const bf16x8*)&Bh[r][c];
                    bl[n] = *(const bf16x8*)&Bl[r][c];
                }
                #pragma unroll
                for (int m = 0; m < 4; ++m)
                    #pragma unroll
                    for (int n = 0; n < 2; ++n) {
                        acc[m][n] = __builtin_amdgcn_mfma_f32_16x16x32_bf16(ah[m], bh[n], acc[m][n], 0, 0, 0);
                        acc[m][n] = __builtin_amdgcn_mfma_f32_16x16x32_bf16(ah[m], bl[n], acc[m][n], 0, 0, 0);
                        acc[m][n] = __builtin_amdgcn_mfma_f32_16x16x32_bf16(al[m], bh[n], acc[m][n], 0, 0, 0);
                    }
            }
        }
        __syncthreads();
    }

    const int cr = (lane >> 4) * 4;
    #pragma unroll
    for (int n = 0; n < 4; ++n) {
        const int col = wc + n * 16 + l15;
        if (col < 96) {
            const float bv = bias[col];
            #pragma unroll
            for (int m = 0; m < 4; ++m)
                #pragma unroll
                for (int r = 0; r < 4; ++r) {
                    const int row = gm + wr + m * 16 + cr + r;
                    lin[(size_t)row * 96 + col] = acc[m][n][r] + bv;
                }
        }
    }
}

// ---------------------------------------------------------------------------
// bf16 MFMA GEMM: C[M x 256] = A @ Bt^T + bias (XCD-pinned rows).
// Bt staged via global_load_lds; A via gload_lds when bf16, reg-staged cvt
// when f32.
// ---------------------------------------------------------------------------
template<bool A_F32, bool OUT_BF16>
__global__ __launch_bounds__(256)
void gemm_bf16_kernel(const void* __restrict__ Ap,
                      const unsigned short* __restrict__ Bt,
                      const float* __restrict__ bias,
                      void* __restrict__ C)
{
    __shared__ unsigned short As[128][64];
    __shared__ unsigned short Bs[128][64];

    const int tid  = threadIdx.x;
    const int lane = tid & 63;
    const int wid  = tid >> 6;
    const int gm = ((blockIdx.x & 7) << 12) + ((blockIdx.x >> 3) << 7);
    const int gn = blockIdx.y * 128;
    const int wr = (wid >> 1) * 64;
    const int wc = (wid & 1) * 64;
    const int l15 = lane & 15;
    const int lk  = (lane >> 4) * 8;
    const int rl  = lane >> 3;
    const int ch  = (lane & 7) ^ (rl & 7);

    f32x4 acc[4][4];
    #pragma unroll
    for (int m = 0; m < 4; ++m)
        #pragma unroll
        for (int n = 0; n < 4; ++n)
            #pragma unroll
            for (int r = 0; r < 4; ++r) acc[m][n][r] = 0.f;

    for (int k0 = 0; k0 < 256; k0 += 64) {
        #pragma unroll
        for (int it = 0; it < 4; ++it) {
            const int br = it * 32 + wid * 8;
            gload16(&Bt[(size_t)(gn + br + rl) * 256 + k0 + ch * 8], &Bs[br][0]);
        }
        if (A_F32) {
            #pragma unroll
            for (int it = 0; it < 4; ++it) {
                const int chunk = it * 256 + tid;
                const int row = chunk >> 3;
                const int kc  = (chunk & 7) << 3;
                const float4* src = (const float4*)&((const float*)Ap)[(size_t)(gm + row) * 256 + k0 + kc];
                const float4 a = src[0], b = src[1];
                float f[8] = {a.x, a.y, a.z, a.w, b.x, b.y, b.z, b.w};
                unsigned short h[8];
                #pragma unroll
                for (int j = 0; j < 8; ++j) h[j] = f2b(f[j]);
                *(uint4*)&As[row][SWZ(row, kc)] = *(const uint4*)h;
            }
        } else {
            #pragma unroll
            for (int it = 0; it < 4; ++it) {
                const int br = it * 32 + wid * 8;
                gload16(&((const unsigned short*)Ap)[(size_t)(gm + br + rl) * 256 + k0 + ch * 8], &As[br][0]);
            }
        }
        __syncthreads();

        #pragma unroll
        for (int kk = 0; kk < 64; kk += 32) {
            bf16x8 a[4], b[4];
            #pragma unroll
            for (int m = 0; m < 4; ++m) {
                const int r = wr + m * 16 + l15;
                a[m] = *(const bf16x8*)&As[r][SWZ(r, kk + lk)];
            }
            #pragma unroll
            for (int n = 0; n < 4; ++n) {
                const int r = wc + n * 16 + l15;
                b[n] = *(const bf16x8*)&Bs[r][SWZ(r, kk + lk)];
            }
            #pragma unroll
            for (int m = 0; m < 4; ++m)
                #pragma unroll
                for (int n = 0; n < 4; ++n)
                    acc[m][n] = __builtin_amdgcn_mfma_f32_16x16x32_bf16(a[m], b[n], acc[m][n], 0, 0, 0);
        }
        __syncthreads();
    }

    const int cr = (lane >> 4) * 4;
    #pragma unroll
    for (int n = 0; n < 4; ++n) {
        const int col = gn + wc + n * 16 + l15;
        const float bv = bias[col];
        #pragma unroll
        for (int m = 0; m < 4; ++m) {
            #pragma unroll
            for (int r = 0; r < 4; ++r) {
                const int row = gm + wr + m * 16 + cr + r;
                const float v = acc[m][n][r] + bv;
                if (OUT_BF16)
                    ((unsigned short*)C)[(size_t)row * 256 + col] = f2b(v);
                else
                    ((float*)C)[(size_t)row * 256 + col] = v;
            }
        }
    }
}

// ---------------------------------------------------------------------------
// Sampling: block = 8 queries (XCD-pinned batch). Phase 1: all 256 threads
// (8 queries x 32 (h,p)) compute softmax/tanh corner weights + packed coords.
// Phase 2: 2 passes, 64 lanes per query, uint2 gathers (4 bf16 ch/lane).
// ---------------------------------------------------------------------------
__global__ __launch_bounds__(256)
void sample_gather_kernel(const unsigned short* __restrict__ projv, // [B][4096][256] bf16
                          const float* __restrict__ lin,            // [M][96]
                          const float* __restrict__ refp,           // [M][2]
                          unsigned short* __restrict__ sampled)     // [M][256] bf16
{
    __shared__ float4 s_w[8][32];
    __shared__ unsigned s_xy[8][32];

    const int i = blockIdx.x;
    const int b = i & 7;                          // batch == XCD
    const int bn0 = (b << 12) + ((i >> 3) << 3);  // first of 8 queries
    const int t = threadIdx.x;

    {
        const int sub = t >> 5;        // 0..7
        const int q = t & 31;          // h*4 + p
        const int h = q >> 2;
        const int p = q & 3;
        const int bn = bn0 + sub;
        const float2 rp = *(const float2*)&refp[(size_t)bn * 2];
        const float2 ol = *(const float2*)&lin[(size_t)bn * 96 + h * 8 + p * 2];
        const float al  = lin[(size_t)bn * 96 + 64 + q];

        float mx = al;
        mx = fmaxf(mx, __shfl_xor(mx, 1));
        mx = fmaxf(mx, __shfl_xor(mx, 2));
        float e = expf(al - mx);
        float s = e;
        s += __shfl_xor(s, 1);
        s += __shfl_xor(s, 2);
        const float aw = e / s;

        const float lx = fminf(fmaxf(rp.x + tanhf(ol.x) * 0.5f, 0.f), 1.f);
        const float ly = fminf(fmaxf(rp.y + tanhf(ol.y) * 0.5f, 0.f), 1.f);
        const float x = lx * (float)IMG - 0.5f;
        const float y = ly * (float)IMG - 0.5f;
        const float x0f = floorf(x), y0f = floorf(y);
        const int x0 = (int)x0f, y0 = (int)y0f;
        const float wx1 = x - x0f, wx0 = 1.f - wx1;
        const float wy1 = y - y0f, wy0 = 1.f - wy1;
        const bool vx0 = (x0 >= 0), vx1 = (x0 + 1 < IMG);
        const bool vy0 = (y0 >= 0), vy1 = (y0 + 1 < IMG);
        float4 w;
        w.x = (vx0 && vy0) ? wx0 * wy0 * aw : 0.f;
        w.y = (vx1 && vy0) ? wx1 * wy0 * aw : 0.f;
        w.z = (vx0 && vy1) ? wx0 * wy1 * aw : 0.f;
        w.w = (vx1 && vy1) ? wx1 * wy1 * aw : 0.f;
        const int x0c = min(max(x0, 0), IMG - 1), x1c = min(max(x0 + 1, 0), IMG - 1);
        const int y0c = min(max(y0, 0), IMG - 1), y1c = min(max(y0 + 1, 0), IMG - 1);
        s_w[sub][q] = w;
        s_xy[sub][q] = (unsigned)x0c | ((unsigned)x1c << 8) | ((unsigned)y0c << 16) | ((unsigned)y1c << 24);
    }
    __syncthreads();

    const int l = t & 63;
    const int h2 = l >> 3;
    const int cp = l & 7;
    const unsigned short* vbase = projv + ((size_t)b << 20) + h2 * HDIM + cp * 4;

    #pragma unroll
    for (int pass = 0; pass < 2; ++pass) {
        const int sub = (t >> 6) + pass * 4;
        const int bn = bn0 + sub;

        float a0 = 0.f, a1 = 0.f, a2 = 0.f, a3 = 0.f;
        #pragma unroll
        for (int p = 0; p < 4; ++p) {
            const float4 w = s_w[sub][h2 * 4 + p];
            const unsigned xy = s_xy[sub][h2 * 4 + p];
            const int x0 = xy & 255, x1 = (xy >> 8) & 255;
            const int y0 = (xy >> 16) & 255, y1 = xy >> 24;
            const uint2 u00 = *(const uint2*)&vbase[(((y0 << 6) + x0) << 8)];
            const uint2 u01 = *(const uint2*)&vbase[(((y0 << 6) + x1) << 8)];
            const uint2 u10 = *(const uint2*)&vbase[(((y1 << 6) + x0) << 8)];
            const uint2 u11 = *(const uint2*)&vbase[(((y1 << 6) + x1) << 8)];
            a0 += w.x * b2f((unsigned short)(u00.x & 0xffff)) + w.y * b2f((unsigned short)(u01.x & 0xffff))
                + w.z * b2f((unsigned short)(u10.x & 0xffff)) + w.w * b2f((unsigned short)(u11.x & 0xffff));
            a1 += w.x * b2f((unsigned short)(u00.x >> 16)) + w.y * b2f((unsigned short)(u01.x >> 16))
                + w.z * b2f((unsigned short)(u10.x >> 16)) + w.w * b2f((unsigned short)(u11.x >> 16));
            a2 += w.x * b2f((unsigned short)(u00.y & 0xffff)) + w.y * b2f((unsigned short)(u01.y & 0xffff))
                + w.z * b2f((unsigned short)(u10.y & 0xffff)) + w.w * b2f((unsigned short)(u11.y & 0xffff));
            a3 += w.x * b2f((unsigned short)(u00.y >> 16)) + w.y * b2f((unsigned short)(u01.y >> 16))
                + w.z * b2f((unsigned short)(u10.y >> 16)) + w.w * b2f((unsigned short)(u11.y >> 16));
        }
        uint2 outp;
        outp.x = (unsigned)f2b(a0) | ((unsigned)f2b(a1) << 16);
        outp.y = (unsigned)f2b(a2) | ((unsigned)f2b(a3) << 16);
        *(uint2*)&sampled[(size_t)bn * 256 + h2 * HDIM + cp * 4] = outp;
    }
}

// ---------------------------------------------------------------------------
extern "C" void kernel_launch(void* const* d_in, const int* in_sizes, int n_in,
                              void* d_out, int out_size, void* d_ws, size_t ws_size,
                              hipStream_t stream)
{
    const float* query  = (const float*)d_in[0];
    const float* value  = (const float*)d_in[1];
    const float* refp   = (const float*)d_in[2];
    const float* W_off  = (const float*)d_in[3];
    const float* b_off  = (const float*)d_in[4];
    const float* W_attn = (const float*)d_in[5];
    const float* b_attn = (const float*)d_in[6];
    const float* W_val  = (const float*)d_in[7];
    const float* b_val  = (const float*)d_in[8];
    const float* W_out  = (const float*)d_in[9];
    const float* b_out  = (const float*)d_in[10];
    float* out = (float*)d_out;

    // workspace layout
    char* ws = (char*)d_ws;
    unsigned short* projv    = (unsigned short*)ws; ws += (size_t)MTOT * 256 * 2;
    unsigned short* sampled  = (unsigned short*)ws; ws += (size_t)MTOT * 256 * 2;
    float*          lin      = (float*)ws;          ws += (size_t)MTOT * 96 * 4;
    unsigned short* Wv_t     = (unsigned short*)ws; ws += 256 * 256 * 2;
    unsigned short* Wo_t     = (unsigned short*)ws; ws += 256 * 256 * 2;
    unsigned short* Wl_h     = (unsigned short*)ws; ws += 128 * 256 * 2;
    unsigned short* Wl_l     = (unsigned short*)ws; ws += 128 * 256 * 2;
    float*          bias_lin = (float*)ws;          ws += 128 * 4;

    dim3 blk(256);

    // 1) weight prep
    cvt_weights_kernel<<<dim3(256), blk, 0, stream>>>(W_val, W_out, W_off, W_attn, b_off, b_attn,
                                                      Wv_t, Wo_t, Wl_h, Wl_l, bias_lin);

    // 2) value projection (XCD-pinned): projv = value @ W_val + b_val -> bf16
    gemm_bf16_kernel<true, true><<<dim3(MTOT / 128, 2), blk, 0, stream>>>(value, Wv_t, b_val, projv);

    // 3) offset+attn logits via split-precision MFMA (XCD-pinned)
    lin_gemm_kernel<<<dim3(MTOT / 128), blk, 0, stream>>>(query, Wl_h, Wl_l, bias_lin, lin);

    // 4) sampling/gather (XCD-pinned batch -> L2-resident projv & lin)
    sample_gather_kernel<<<dim3(MTOT / 8), blk, 0, stream>>>(projv, lin, refp, sampled);

    // 5) output projection (XCD-pinned): out = sampled @ W_out + b_out -> f32
    gemm_bf16_kernel<false, false><<<dim3(MTOT / 128, 2), blk, 0, stream>>>(sampled, Wo_t, b_out, out);
}

// Round 7
// 73.284 us; speedup vs baseline: 1.0088x; 1.0088x over previous
//
#include <hip/hip_runtime.h>
#include <math.h>

#define NHEAD 8
#define NPT 4
#define HDIM 32
#define IMG 64      // H = W = 64
#define CDIM 256
#define NQ 4096
#define BATCH 8
#define MTOT (BATCH * NQ)   // 32768

typedef __attribute__((ext_vector_type(8))) short bf16x8;
typedef __attribute__((ext_vector_type(4))) float f32x4;

__device__ __forceinline__ unsigned short f2b(float f) {
    union { float f; unsigned u; } v; v.f = f;
    unsigned r = (v.u + 0x7FFFu + ((v.u >> 16) & 1u)) >> 16;
    return (unsigned short)r;
}
__device__ __forceinline__ float b2f(unsigned short u) {
    union { unsigned u; float f; } v; v.u = ((unsigned)u) << 16;
    return v.f;
}

// XOR swizzles (ushort units). BK=64 tiles: 8 chunks/row; BK=32: 4 chunks/row.
#define SWZ(row, col)   ((col) ^ (((row) & 7) << 3))
#define SWZ32(row, col) ((col) ^ (((row) & 3) << 3))

// Async global->LDS, 16B per lane; dest = wave-uniform base + lane*16.
__device__ __forceinline__ void gload16(const void* src, void* ldsbase) {
    __builtin_amdgcn_global_load_lds(
        (const __attribute__((address_space(1))) void*)src,
        (__attribute__((address_space(3))) void*)ldsbase, 16, 0, 0);
}

// XCD pinning: batch = blockIdx.x & 7 -> XCD (blockIdx % 8) round-robin.
// Each XCD owns one batch's projv/lin/sampled slice -> L2-resident.

// ---------------------------------------------------------------------------
// Weight prep.
// ---------------------------------------------------------------------------
__global__ __launch_bounds__(256)
void cvt_weights_kernel(const float* __restrict__ Wv, const float* __restrict__ Wo,
                        const float* __restrict__ Woff, const float* __restrict__ Wattn,
                        const float* __restrict__ boff, const float* __restrict__ battn,
                        unsigned short* __restrict__ Wv_t, unsigned short* __restrict__ Wo_t,
                        unsigned short* __restrict__ Wl_h, unsigned short* __restrict__ Wl_l,
                        float* __restrict__ bias_lin)
{
    int tid = blockIdx.x * 256 + threadIdx.x;   // 0 .. 65535
    int n = tid & 255, k = tid >> 8;
    Wv_t[n * 256 + k] = f2b(Wv[k * 256 + n]);
    Wo_t[n * 256 + k] = f2b(Wo[k * 256 + n]);
    if (tid < 128 * 256) {
        int nn = tid >> 8;
        int kk = tid & 255;
        float v = (nn < 64) ? Woff[kk * 64 + nn]
                : (nn < 96) ? Wattn[kk * 32 + (nn - 64)] : 0.f;
        unsigned short hi = f2b(v);
        unsigned short lo = f2b(v - b2f(hi));
        Wl_h[nn * 256 + kk] = hi;
        Wl_l[nn * 256 + kk] = lo;
    }
    if (tid < 128)
        bias_lin[tid] = (tid < 64) ? boff[tid] : (tid < 96) ? battn[tid - 64] : 0.f;
}

// ---------------------------------------------------------------------------
// Combined launch: blocks [0,512) = value projection (bf16 MFMA, BK=64),
// blocks [512,768) = offset/attn logits (split-precision 3-term MFMA, BK=32).
// Both XCD-pinned (batch = blockIdx & 7). LDS union = 32 KB.
// ---------------------------------------------------------------------------
__global__ __launch_bounds__(256)
void fused_gemms_kernel(const float* __restrict__ value,
                        const float* __restrict__ query,
                        const unsigned short* __restrict__ Wv_t,
                        const unsigned short* __restrict__ Wl_h,
                        const unsigned short* __restrict__ Wl_l,
                        const float* __restrict__ b_val,
                        const float* __restrict__ bias_lin,
                        unsigned short* __restrict__ projv,
                        float* __restrict__ lin)
{
    __shared__ char smem[32768];

    const int tid  = threadIdx.x;
    const int lane = tid & 63;
    const int wid  = tid >> 6;
    const int wr = (wid >> 1) * 64;
    const int wc = (wid & 1) * 64;
    const int l15 = lane & 15;
    const int lk  = (lane >> 4) * 8;

    f32x4 acc[4][4];
    #pragma unroll
    for (int m = 0; m < 4; ++m)
        #pragma unroll
        for (int n = 0; n < 4; ++n)
            #pragma unroll
            for (int r = 0; r < 4; ++r) acc[m][n][r] = 0.f;

    if (blockIdx.x < 512) {
        // ================= value projection =================
        unsigned short (*As)[64] = (unsigned short(*)[64])smem;
        unsigned short (*Bs)[64] = (unsigned short(*)[64])(smem + 16384);
        const int bx = blockIdx.x;
        const int gm = ((bx & 7) << 12) + (((bx >> 3) & 31) << 7);
        const int gn = (bx >> 8) << 7;
        const int rl  = lane >> 3;
        const int ch  = (lane & 7) ^ (rl & 7);

        for (int k0 = 0; k0 < 256; k0 += 64) {
            #pragma unroll
            for (int it = 0; it < 4; ++it) {
                const int br = it * 32 + wid * 8;
                gload16(&Wv_t[(size_t)(gn + br + rl) * 256 + k0 + ch * 8], &Bs[br][0]);
            }
            #pragma unroll
            for (int it = 0; it < 4; ++it) {
                const int chunk = it * 256 + tid;
                const int row = chunk >> 3;
                const int kc  = (chunk & 7) << 3;
                const float4* src = (const float4*)&value[(size_t)(gm + row) * 256 + k0 + kc];
                const float4 a = src[0], b = src[1];
                float f[8] = {a.x, a.y, a.z, a.w, b.x, b.y, b.z, b.w};
                unsigned short h[8];
                #pragma unroll
                for (int j = 0; j < 8; ++j) h[j] = f2b(f[j]);
                *(uint4*)&As[row][SWZ(row, kc)] = *(const uint4*)h;
            }
            __syncthreads();

            #pragma unroll
            for (int kk = 0; kk < 64; kk += 32) {
                bf16x8 a[4], b[4];
                #pragma unroll
                for (int m = 0; m < 4; ++m) {
                    const int r = wr + m * 16 + l15;
                    a[m] = *(const bf16x8*)&As[r][SWZ(r, kk + lk)];
                }
                #pragma unroll
                for (int n = 0; n < 4; ++n) {
                    const int r = wc + n * 16 + l15;
                    b[n] = *(const bf16x8*)&Bs[r][SWZ(r, kk + lk)];
                }
                #pragma unroll
                for (int m = 0; m < 4; ++m)
                    #pragma unroll
                    for (int n = 0; n < 4; ++n)
                        acc[m][n] = __builtin_amdgcn_mfma_f32_16x16x32_bf16(a[m], b[n], acc[m][n], 0, 0, 0);
            }
            __syncthreads();
        }

        const int cr = (lane >> 4) * 4;
        #pragma unroll
        for (int n = 0; n < 4; ++n) {
            const int col = gn + wc + n * 16 + l15;
            const float bv = b_val[col];
            #pragma unroll
            for (int m = 0; m < 4; ++m)
                #pragma unroll
                for (int r = 0; r < 4; ++r) {
                    const int row = gm + wr + m * 16 + cr + r;
                    projv[(size_t)row * 256 + col] = f2b(acc[m][n][r] + bv);
                }
        }
    } else {
        // ================= offset/attn logits (BK=32) =================
        unsigned short (*Ah)[32] = (unsigned short(*)[32])smem;
        unsigned short (*Al)[32] = (unsigned short(*)[32])(smem + 8192);
        unsigned short (*Bh)[32] = (unsigned short(*)[32])(smem + 16384);
        unsigned short (*Bl)[32] = (unsigned short(*)[32])(smem + 24576);
        const int lbx = blockIdx.x - 512;
        const int gm = ((lbx & 7) << 12) + ((lbx >> 3) << 7);
        const int rs = lane >> 2;       // row within 16-row stripe
        const int cc = lane & 3;        // 16B chunk within row

        for (int k0 = 0; k0 < 256; k0 += 32) {
            // B staging via global_load_lds (linear LDS, pre-swizzled source)
            #pragma unroll
            for (int i = 0; i < 2; ++i) {
                const int row = wid * 32 + i * 16 + rs;
                const int cs = (cc ^ (row & 3)) << 3;   // ushort offset
                gload16(&Wl_h[(size_t)row * 256 + k0 + cs], &Bh[wid * 32 + i * 16][0]);
                gload16(&Wl_l[(size_t)row * 256 + k0 + cs], &Bl[wid * 32 + i * 16][0]);
            }
            // A staging: reg-staged f32 -> hi/lo bf16 split
            #pragma unroll
            for (int it = 0; it < 2; ++it) {
                const int chunk = it * 256 + tid;   // 0..511
                const int row = chunk >> 2;
                const int kc  = (chunk & 3) << 3;
                const float4* src = (const float4*)&query[(size_t)(gm + row) * 256 + k0 + kc];
                const float4 a = src[0], b = src[1];
                float f[8] = {a.x, a.y, a.z, a.w, b.x, b.y, b.z, b.w};
                unsigned short h[8], l[8];
                #pragma unroll
                for (int j = 0; j < 8; ++j) {
                    h[j] = f2b(f[j]);
                    l[j] = f2b(f[j] - b2f(h[j]));
                }
                const int sc = SWZ32(row, kc);
                *(uint4*)&Ah[row][sc] = *(const uint4*)h;
                *(uint4*)&Al[row][sc] = *(const uint4*)l;
            }
            __syncthreads();

            bf16x8 ah[4], al[4];
            #pragma unroll
            for (int m = 0; m < 4; ++m) {
                const int r = wr + m * 16 + l15;
                const int c = SWZ32(r, lk);
                ah[m] = *(const bf16x8*)&Ah[r][c];
                al[m] = *(const bf16x8*)&Al[r][c];
            }
            if (wc == 0) {
                bf16x8 bh[4], bl[4];
                #pragma unroll
                for (int n = 0; n < 4; ++n) {
                    const int r = n * 16 + l15;
                    const int c = SWZ32(r, lk);
                    bh[n] = *(const bf16x8*)&Bh[r][c];
                    bl[n] = *(const bf16x8*)&Bl[r][c];
                }
                #pragma unroll
                for (int m = 0; m < 4; ++m)
                    #pragma unroll
                    for (int n = 0; n < 4; ++n) {
                        acc[m][n] = __builtin_amdgcn_mfma_f32_16x16x32_bf16(ah[m], bh[n], acc[m][n], 0, 0, 0);
                        acc[m][n] = __builtin_amdgcn_mfma_f32_16x16x32_bf16(ah[m], bl[n], acc[m][n], 0, 0, 0);
                        acc[m][n] = __builtin_amdgcn_mfma_f32_16x16x32_bf16(al[m], bh[n], acc[m][n], 0, 0, 0);
                    }
            } else {
                bf16x8 bh[2], bl[2];
                #pragma unroll
                for (int n = 0; n < 2; ++n) {
                    const int r = 64 + n * 16 + l15;
                    const int c = SWZ32(r, lk);
                    bh[n] = *(const bf16x8*)&Bh[r][c];
                    bl[n] = *(const bf16x8*)&Bl[r][c];
                }
                #pragma unroll
                for (int m = 0; m < 4; ++m)
                    #pragma unroll
                    for (int n = 0; n < 2; ++n) {
                        acc[m][n] = __builtin_amdgcn_mfma_f32_16x16x32_bf16(ah[m], bh[n], acc[m][n], 0, 0, 0);
                        acc[m][n] = __builtin_amdgcn_mfma_f32_16x16x32_bf16(ah[m], bl[n], acc[m][n], 0, 0, 0);
                        acc[m][n] = __builtin_amdgcn_mfma_f32_16x16x32_bf16(al[m], bh[n], acc[m][n], 0, 0, 0);
                    }
            }
            __syncthreads();
        }

        const int cr = (lane >> 4) * 4;
        #pragma unroll
        for (int n = 0; n < 4; ++n) {
            const int col = wc + n * 16 + l15;
            if (col < 96) {
                const float bv = bias_lin[col];
                #pragma unroll
                for (int m = 0; m < 4; ++m)
                    #pragma unroll
                    for (int r = 0; r < 4; ++r) {
                        const int row = gm + wr + m * 16 + cr + r;
                        lin[(size_t)row * 96 + col] = acc[m][n][r] + bv;
                    }
            }
        }
    }
}

// ---------------------------------------------------------------------------
// bf16 MFMA GEMM (out-proj): C[M x 256] = A(bf16) @ Bt^T + bias, f32 out.
// ---------------------------------------------------------------------------
__global__ __launch_bounds__(256)
void gemm_out_kernel(const unsigned short* __restrict__ Ap,
                     const unsigned short* __restrict__ Bt,
                     const float* __restrict__ bias,
                     float* __restrict__ C)
{
    __shared__ unsigned short As[128][64];
    __shared__ unsigned short Bs[128][64];

    const int tid  = threadIdx.x;
    const int lane = tid & 63;
    const int wid  = tid >> 6;
    const int gm = ((blockIdx.x & 7) << 12) + ((blockIdx.x >> 3) << 7);
    const int gn = blockIdx.y * 128;
    const int wr = (wid >> 1) * 64;
    const int wc = (wid & 1) * 64;
    const int l15 = lane & 15;
    const int lk  = (lane >> 4) * 8;
    const int rl  = lane >> 3;
    const int ch  = (lane & 7) ^ (rl & 7);

    f32x4 acc[4][4];
    #pragma unroll
    for (int m = 0; m < 4; ++m)
        #pragma unroll
        for (int n = 0; n < 4; ++n)
            #pragma unroll
            for (int r = 0; r < 4; ++r) acc[m][n][r] = 0.f;

    for (int k0 = 0; k0 < 256; k0 += 64) {
        #pragma unroll
        for (int it = 0; it < 4; ++it) {
            const int br = it * 32 + wid * 8;
            gload16(&Bt[(size_t)(gn + br + rl) * 256 + k0 + ch * 8], &Bs[br][0]);
            gload16(&Ap[(size_t)(gm + br + rl) * 256 + k0 + ch * 8], &As[br][0]);
        }
        __syncthreads();

        #pragma unroll
        for (int kk = 0; kk < 64; kk += 32) {
            bf16x8 a[4], b[4];
            #pragma unroll
            for (int m = 0; m < 4; ++m) {
                const int r = wr + m * 16 + l15;
                a[m] = *(const bf16x8*)&As[r][SWZ(r, kk + lk)];
            }
            #pragma unroll
            for (int n = 0; n < 4; ++n) {
                const int r = wc + n * 16 + l15;
                b[n] = *(const bf16x8*)&Bs[r][SWZ(r, kk + lk)];
            }
            #pragma unroll
            for (int m = 0; m < 4; ++m)
                #pragma unroll
                for (int n = 0; n < 4; ++n)
                    acc[m][n] = __builtin_amdgcn_mfma_f32_16x16x32_bf16(a[m], b[n], acc[m][n], 0, 0, 0);
        }
        __syncthreads();
    }

    const int cr = (lane >> 4) * 4;
    #pragma unroll
    for (int n = 0; n < 4; ++n) {
        const int col = gn + wc + n * 16 + l15;
        const float bv = bias[col];
        #pragma unroll
        for (int m = 0; m < 4; ++m)
            #pragma unroll
            for (int r = 0; r < 4; ++r) {
                const int row = gm + wr + m * 16 + cr + r;
                C[(size_t)row * 256 + col] = acc[m][n][r] + bv;
            }
    }
}

// ---------------------------------------------------------------------------
// Sampling: block = 8 queries (XCD-pinned batch). Phase 1: all 256 threads
// (8 queries x 32 (h,p)) compute softmax/tanh corner weights + packed coords.
// Phase 2: 2 passes, 64 lanes per query, uint2 gathers (4 bf16 ch/lane).
// ---------------------------------------------------------------------------
__global__ __launch_bounds__(256)
void sample_gather_kernel(const unsigned short* __restrict__ projv, // [B][4096][256] bf16
                          const float* __restrict__ lin,            // [M][96]
                          const float* __restrict__ refp,           // [M][2]
                          unsigned short* __restrict__ sampled)     // [M][256] bf16
{
    __shared__ float4 s_w[8][32];
    __shared__ unsigned s_xy[8][32];

    const int i = blockIdx.x;
    const int b = i & 7;                          // batch == XCD
    const int bn0 = (b << 12) + ((i >> 3) << 3);  // first of 8 queries
    const int t = threadIdx.x;

    {
        const int sub = t >> 5;        // 0..7
        const int q = t & 31;          // h*4 + p
        const int h = q >> 2;
        const int p = q & 3;
        const int bn = bn0 + sub;
        const float2 rp = *(const float2*)&refp[(size_t)bn * 2];
        const float2 ol = *(const float2*)&lin[(size_t)bn * 96 + h * 8 + p * 2];
        const float al  = lin[(size_t)bn * 96 + 64 + q];

        float mx = al;
        mx = fmaxf(mx, __shfl_xor(mx, 1));
        mx = fmaxf(mx, __shfl_xor(mx, 2));
        float e = expf(al - mx);
        float s = e;
        s += __shfl_xor(s, 1);
        s += __shfl_xor(s, 2);
        const float aw = e / s;

        const float lx = fminf(fmaxf(rp.x + tanhf(ol.x) * 0.5f, 0.f), 1.f);
        const float ly = fminf(fmaxf(rp.y + tanhf(ol.y) * 0.5f, 0.f), 1.f);
        const float x = lx * (float)IMG - 0.5f;
        const float y = ly * (float)IMG - 0.5f;
        const float x0f = floorf(x), y0f = floorf(y);
        const int x0 = (int)x0f, y0 = (int)y0f;
        const float wx1 = x - x0f, wx0 = 1.f - wx1;
        const float wy1 = y - y0f, wy0 = 1.f - wy1;
        const bool vx0 = (x0 >= 0), vx1 = (x0 + 1 < IMG);
        const bool vy0 = (y0 >= 0), vy1 = (y0 + 1 < IMG);
        float4 w;
        w.x = (vx0 && vy0) ? wx0 * wy0 * aw : 0.f;
        w.y = (vx1 && vy0) ? wx1 * wy0 * aw : 0.f;
        w.z = (vx0 && vy1) ? wx0 * wy1 * aw : 0.f;
        w.w = (vx1 && vy1) ? wx1 * wy1 * aw : 0.f;
        const int x0c = min(max(x0, 0), IMG - 1), x1c = min(max(x0 + 1, 0), IMG - 1);
        const int y0c = min(max(y0, 0), IMG - 1), y1c = min(max(y0 + 1, 0), IMG - 1);
        s_w[sub][q] = w;
        s_xy[sub][q] = (unsigned)x0c | ((unsigned)x1c << 8) | ((unsigned)y0c << 16) | ((unsigned)y1c << 24);
    }
    __syncthreads();

    const int l = t & 63;
    const int h2 = l >> 3;
    const int cp = l & 7;
    const unsigned short* vbase = projv + ((size_t)b << 20) + h2 * HDIM + cp * 4;

    #pragma unroll
    for (int pass = 0; pass < 2; ++pass) {
        const int sub = (t >> 6) + pass * 4;
        const int bn = bn0 + sub;

        float a0 = 0.f, a1 = 0.f, a2 = 0.f, a3 = 0.f;
        #pragma unroll
        for (int p = 0; p < 4; ++p) {
            const float4 w = s_w[sub][h2 * 4 + p];
            const unsigned xy = s_xy[sub][h2 * 4 + p];
            const int x0 = xy & 255, x1 = (xy >> 8) & 255;
            const int y0 = (xy >> 16) & 255, y1 = xy >> 24;
            const uint2 u00 = *(const uint2*)&vbase[(((y0 << 6) + x0) << 8)];
            const uint2 u01 = *(const uint2*)&vbase[(((y0 << 6) + x1) << 8)];
            const uint2 u10 = *(const uint2*)&vbase[(((y1 << 6) + x0) << 8)];
            const uint2 u11 = *(const uint2*)&vbase[(((y1 << 6) + x1) << 8)];
            a0 += w.x * b2f((unsigned short)(u00.x & 0xffff)) + w.y * b2f((unsigned short)(u01.x & 0xffff))
                + w.z * b2f((unsigned short)(u10.x & 0xffff)) + w.w * b2f((unsigned short)(u11.x & 0xffff));
            a1 += w.x * b2f((unsigned short)(u00.x >> 16)) + w.y * b2f((unsigned short)(u01.x >> 16))
                + w.z * b2f((unsigned short)(u10.x >> 16)) + w.w * b2f((unsigned short)(u11.x >> 16));
            a2 += w.x * b2f((unsigned short)(u00.y & 0xffff)) + w.y * b2f((unsigned short)(u01.y & 0xffff))
                + w.z * b2f((unsigned short)(u10.y & 0xffff)) + w.w * b2f((unsigned short)(u11.y & 0xffff));
            a3 += w.x * b2f((unsigned short)(u00.y >> 16)) + w.y * b2f((unsigned short)(u01.y >> 16))
                + w.z * b2f((unsigned short)(u10.y >> 16)) + w.w * b2f((unsigned short)(u11.y >> 16));
        }
        uint2 outp;
        outp.x = (unsigned)f2b(a0) | ((unsigned)f2b(a1) << 16);
        outp.y = (unsigned)f2b(a2) | ((unsigned)f2b(a3) << 16);
        *(uint2*)&sampled[(size_t)bn * 256 + h2 * HDIM + cp * 4] = outp;
    }
}

// ---------------------------------------------------------------------------
extern "C" void kernel_launch(void* const* d_in, const int* in_sizes, int n_in,
                              void* d_out, int out_size, void* d_ws, size_t ws_size,
                              hipStream_t stream)
{
    const float* query  = (const float*)d_in[0];
    const float* value  = (const float*)d_in[1];
    const float* refp   = (const float*)d_in[2];
    const float* W_off  = (const float*)d_in[3];
    const float* b_off  = (const float*)d_in[4];
    const float* W_attn = (const float*)d_in[5];
    const float* b_attn = (const float*)d_in[6];
    const float* W_val  = (const float*)d_in[7];
    const float* b_val  = (const float*)d_in[8];
    const float* W_out  = (const float*)d_in[9];
    const float* b_out  = (const float*)d_in[10];
    float* out = (float*)d_out;

    // workspace layout
    char* ws = (char*)d_ws;
    unsigned short* projv    = (unsigned short*)ws; ws += (size_t)MTOT * 256 * 2;
    unsigned short* sampled  = (unsigned short*)ws; ws += (size_t)MTOT * 256 * 2;
    float*          lin      = (float*)ws;          ws += (size_t)MTOT * 96 * 4;
    unsigned short* Wv_t     = (unsigned short*)ws; ws += 256 * 256 * 2;
    unsigned short* Wo_t     = (unsigned short*)ws; ws += 256 * 256 * 2;
    unsigned short* Wl_h     = (unsigned short*)ws; ws += 128 * 256 * 2;
    unsigned short* Wl_l     = (unsigned short*)ws; ws += 128 * 256 * 2;
    float*          bias_lin = (float*)ws;          ws += 128 * 4;

    dim3 blk(256);

    // 1) weight prep
    cvt_weights_kernel<<<dim3(256), blk, 0, stream>>>(W_val, W_out, W_off, W_attn, b_off, b_attn,
                                                      Wv_t, Wo_t, Wl_h, Wl_l, bias_lin);

    // 2) value projection + offset/attn logits in ONE launch (768 blocks)
    fused_gemms_kernel<<<dim3(768), blk, 0, stream>>>(value, query, Wv_t, Wl_h, Wl_l,
                                                      b_val, bias_lin, projv, lin);

    // 3) sampling/gather (XCD-pinned batch -> L2-resident projv & lin)
    sample_gather_kernel<<<dim3(MTOT / 8), blk, 0, stream>>>(projv, lin, refp, sampled);

    // 4) output projection: out = sampled @ W_out + b_out -> f32
    gemm_out_kernel<<<dim3(MTOT / 128, 2), blk, 0, stream>>>(sampled, Wo_t, b_out, out);
}

// Round 8
// 72.074 us; speedup vs baseline: 1.0257x; 1.0168x over previous
//
#include <hip/hip_runtime.h>
#include <math.h>

#define NHEAD 8
#define NPT 4
#define HDIM 32
#define IMG 64      // H = W = 64
#define CDIM 256
#define NQ 4096
#define BATCH 8
#define MTOT (BATCH * NQ)   // 32768

typedef __attribute__((ext_vector_type(8))) short bf16x8;
typedef __attribute__((ext_vector_type(4))) float f32x4;

__device__ __forceinline__ unsigned short f2b(float f) {
    union { float f; unsigned u; } v; v.f = f;
    unsigned r = (v.u + 0x7FFFu + ((v.u >> 16) & 1u)) >> 16;
    return (unsigned short)r;
}
__device__ __forceinline__ float b2f(unsigned short u) {
    union { unsigned u; float f; } v; v.u = ((unsigned)u) << 16;
    return v.f;
}

// XOR swizzle for [128][64]-ushort tiles (8 chunks of 16B per row).
#define SWZ(row, col)   ((col) ^ (((row) & 7) << 3))

// Async global->LDS, 16B per lane; dest = wave-uniform base + lane*16.
__device__ __forceinline__ void gload16(const void* src, void* ldsbase) {
    __builtin_amdgcn_global_load_lds(
        (const __attribute__((address_space(1))) void*)src,
        (__attribute__((address_space(3))) void*)ldsbase, 16, 0, 0);
}

// XCD pinning: batch = blockIdx.x & 7 -> XCD (blockIdx % 8) round-robin.

// ---------------------------------------------------------------------------
// value f32 -> bf16 (streaming, grid-stride, 8 floats/thread/iter)
// ---------------------------------------------------------------------------
__global__ __launch_bounds__(256)
void cvt_value_kernel(const float* __restrict__ in, unsigned short* __restrict__ out)
{
    const int n8 = MTOT * 256 / 8;   // 1048576 chunks
    for (int i = blockIdx.x * 256 + threadIdx.x; i < n8; i += 2048 * 256) {
        const float4 a = ((const float4*)in)[i * 2];
        const float4 b = ((const float4*)in)[i * 2 + 1];
        unsigned short us[8] = { f2b(a.x), f2b(a.y), f2b(a.z), f2b(a.w),
                                 f2b(b.x), f2b(b.y), f2b(b.z), f2b(b.w) };
        ((uint4*)out)[i] = *(const uint4*)us;
    }
}

// ---------------------------------------------------------------------------
// Weight prep.
// ---------------------------------------------------------------------------
__global__ __launch_bounds__(256)
void cvt_weights_kernel(const float* __restrict__ Wv, const float* __restrict__ Wo,
                        const float* __restrict__ Woff, const float* __restrict__ Wattn,
                        const float* __restrict__ boff, const float* __restrict__ battn,
                        unsigned short* __restrict__ Wv_t, unsigned short* __restrict__ Wo_t,
                        unsigned short* __restrict__ Wl_h, unsigned short* __restrict__ Wl_l,
                        float* __restrict__ bias_lin)
{
    int tid = blockIdx.x * 256 + threadIdx.x;   // 0 .. 65535
    int n = tid & 255, k = tid >> 8;
    Wv_t[n * 256 + k] = f2b(Wv[k * 256 + n]);
    Wo_t[n * 256 + k] = f2b(Wo[k * 256 + n]);
    if (tid < 128 * 256) {
        int nn = tid >> 8;
        int kk = tid & 255;
        float v = (nn < 64) ? Woff[kk * 64 + nn]
                : (nn < 96) ? Wattn[kk * 32 + (nn - 64)] : 0.f;
        unsigned short hi = f2b(v);
        unsigned short lo = f2b(v - b2f(hi));
        Wl_h[nn * 256 + kk] = hi;
        Wl_l[nn * 256 + kk] = lo;
    }
    if (tid < 128)
        bias_lin[tid] = (tid < 64) ? boff[tid] : (tid < 96) ? battn[tid - 64] : 0.f;
}

// ---------------------------------------------------------------------------
// Combined launch (768 blocks):
//   blocks [0,256)  : offset/attn logits (split-precision, BK=32, A = raw f32
//                     query gload'd to LDS, hi/lo split at fragment read)
//   blocks [256,768): value projection (all-gload bf16, BK=64)
// Long lin blocks first so short val blocks fill the tail. XCD-pinned.
// LDS union = 32 KB.
// ---------------------------------------------------------------------------
__global__ __launch_bounds__(256)
void fused_gemms_kernel(const unsigned short* __restrict__ value_bf,
                        const float* __restrict__ query,
                        const unsigned short* __restrict__ Wv_t,
                        const unsigned short* __restrict__ Wl_h,
                        const unsigned short* __restrict__ Wl_l,
                        const float* __restrict__ b_val,
                        const float* __restrict__ bias_lin,
                        unsigned short* __restrict__ projv,
                        float* __restrict__ lin)
{
    __shared__ char smem[32768];

    const int tid  = threadIdx.x;
    const int lane = tid & 63;
    const int wid  = tid >> 6;
    const int wr = (wid >> 1) * 64;
    const int wc = (wid & 1) * 64;
    const int l15 = lane & 15;
    const int lk  = (lane >> 4) * 8;

    f32x4 acc[4][4];
    #pragma unroll
    for (int m = 0; m < 4; ++m)
        #pragma unroll
        for (int n = 0; n < 4; ++n)
            #pragma unroll
            for (int r = 0; r < 4; ++r) acc[m][n][r] = 0.f;

    if (blockIdx.x >= 256) {
        // ================= value projection (all-gload bf16) =================
        unsigned short (*As)[64] = (unsigned short(*)[64])smem;
        unsigned short (*Bs)[64] = (unsigned short(*)[64])(smem + 16384);
        const int bx = blockIdx.x - 256;
        const int gm = ((bx & 7) << 12) + (((bx >> 3) & 31) << 7);
        const int gn = (bx >> 8) << 7;
        const int rl  = lane >> 3;                // 0..7
        const int ch  = (lane & 7) ^ rl;          // pre-swizzled source chunk

        for (int k0 = 0; k0 < 256; k0 += 64) {
            #pragma unroll
            for (int it = 0; it < 4; ++it) {
                const int br = it * 32 + wid * 8;
                gload16(&Wv_t[(size_t)(gn + br + rl) * 256 + k0 + ch * 8], &Bs[br][0]);
                gload16(&value_bf[(size_t)(gm + br + rl) * 256 + k0 + ch * 8], &As[br][0]);
            }
            __syncthreads();

            #pragma unroll
            for (int kk = 0; kk < 64; kk += 32) {
                bf16x8 a[4], b[4];
                #pragma unroll
                for (int m = 0; m < 4; ++m) {
                    const int r = wr + m * 16 + l15;
                    a[m] = *(const bf16x8*)&As[r][SWZ(r, kk + lk)];
                }
                #pragma unroll
                for (int n = 0; n < 4; ++n) {
                    const int r = wc + n * 16 + l15;
                    b[n] = *(const bf16x8*)&Bs[r][SWZ(r, kk + lk)];
                }
                #pragma unroll
                for (int m = 0; m < 4; ++m)
                    #pragma unroll
                    for (int n = 0; n < 4; ++n)
                        acc[m][n] = __builtin_amdgcn_mfma_f32_16x16x32_bf16(a[m], b[n], acc[m][n], 0, 0, 0);
            }
            __syncthreads();
        }

        const int cr = (lane >> 4) * 4;
        #pragma unroll
        for (int n = 0; n < 4; ++n) {
            const int col = gn + wc + n * 16 + l15;
            const float bv = b_val[col];
            #pragma unroll
            for (int m = 0; m < 4; ++m)
                #pragma unroll
                for (int r = 0; r < 4; ++r) {
                    const int row = gm + wr + m * 16 + cr + r;
                    projv[(size_t)row * 256 + col] = f2b(acc[m][n][r] + bv);
                }
        }
    } else {
        // ====== offset/attn logits (BK=32, A = f32 query in LDS) ======
        float (*Aq)[32] = (float(*)[32])smem;                         // 16 KB
        unsigned short (*Bh)[32] = (unsigned short(*)[32])(smem + 16384); // 8 KB
        unsigned short (*Bl)[32] = (unsigned short(*)[32])(smem + 24576); // 8 KB
        const int lbx = blockIdx.x;
        const int gm = ((lbx & 7) << 12) + ((lbx >> 3) << 7);
        // A staging lanes: 8 rows x 8 chunks of 16B (4 f32)
        const int rla = lane >> 3;                 // 0..7
        const int ca  = (lane & 7) ^ rla;          // pre-swizzled chunk (x4 f32)
        // B staging lanes: 16 rows x 4 chunks of 16B (8 ushort)
        const int rsb = lane >> 2;                 // 0..15
        const int cb  = (lane & 3) ^ (rsb & 3);    // pre-swizzled chunk (x8 us)

        for (int k0 = 0; k0 < 256; k0 += 32) {
            // A: 128 rows x 32 f32; 16 gloads total, 4 per wave
            #pragma unroll
            for (int i = 0; i < 4; ++i) {
                const int ar = wid * 32 + i * 8;
                gload16(&query[(size_t)(gm + ar + rla) * 256 + k0 + ca * 4], &Aq[ar][0]);
            }
            // B: 128 rows x 32 ushort each; 8 gloads per array, 2 per wave
            #pragma unroll
            for (int i = 0; i < 2; ++i) {
                const int br = wid * 32 + i * 16;
                gload16(&Wl_h[(size_t)(br + rsb) * 256 + k0 + cb * 8], &Bh[br][0]);
                gload16(&Wl_l[(size_t)(br + rsb) * 256 + k0 + cb * 8], &Bl[br][0]);
            }
            __syncthreads();

            // A fragments: read f32, split hi/lo in registers
            bf16x8 ah[4], al[4];
            #pragma unroll
            for (int m = 0; m < 4; ++m) {
                const int r = wr + m * 16 + l15;
                const int c0 = ((lk >> 2) ^ (r & 7)) << 2;
                const int c1 = (((lk >> 2) + 1) ^ (r & 7)) << 2;
                const f32x4 qa = *(const f32x4*)&Aq[r][c0];
                const f32x4 qb = *(const f32x4*)&Aq[r][c1];
                float f[8] = {qa.x, qa.y, qa.z, qa.w, qb.x, qb.y, qb.z, qb.w};
                unsigned short h[8], l[8];
                #pragma unroll
                for (int j = 0; j < 8; ++j) {
                    h[j] = f2b(f[j]);
                    l[j] = f2b(f[j] - b2f(h[j]));
                }
                ah[m] = *(const bf16x8*)h;
                al[m] = *(const bf16x8*)l;
            }

            const int nN = (wc == 0) ? 4 : 2;
            #pragma unroll
            for (int n = 0; n < 4; ++n) {
                if (n >= nN) break;
                const int r = wc + n * 16 + l15;
                const int c = ((lk >> 3) ^ (r & 3)) << 3;
                const bf16x8 bh = *(const bf16x8*)&Bh[r][c];
                const bf16x8 bl = *(const bf16x8*)&Bl[r][c];
                #pragma unroll
                for (int m = 0; m < 4; ++m) {
                    acc[m][n] = __builtin_amdgcn_mfma_f32_16x16x32_bf16(ah[m], bh, acc[m][n], 0, 0, 0);
                    acc[m][n] = __builtin_amdgcn_mfma_f32_16x16x32_bf16(ah[m], bl, acc[m][n], 0, 0, 0);
                    acc[m][n] = __builtin_amdgcn_mfma_f32_16x16x32_bf16(al[m], bh, acc[m][n], 0, 0, 0);
                }
            }
            __syncthreads();
        }

        const int cr = (lane >> 4) * 4;
        #pragma unroll
        for (int n = 0; n < 4; ++n) {
            const int col = wc + n * 16 + l15;
            if (col < 96) {
                const float bv = bias_lin[col];
                #pragma unroll
                for (int m = 0; m < 4; ++m)
                    #pragma unroll
                    for (int r = 0; r < 4; ++r) {
                        const int row = gm + wr + m * 16 + cr + r;
                        lin[(size_t)row * 96 + col] = acc[m][n][r] + bv;
                    }
            }
        }
    }
}

// ---------------------------------------------------------------------------
// bf16 MFMA GEMM (out-proj): C[M x 256] = A(bf16) @ Bt^T + bias, f32 out.
// ---------------------------------------------------------------------------
__global__ __launch_bounds__(256)
void gemm_out_kernel(const unsigned short* __restrict__ Ap,
                     const unsigned short* __restrict__ Bt,
                     const float* __restrict__ bias,
                     float* __restrict__ C)
{
    __shared__ unsigned short As[128][64];
    __shared__ unsigned short Bs[128][64];

    const int tid  = threadIdx.x;
    const int lane = tid & 63;
    const int wid  = tid >> 6;
    const int gm = ((blockIdx.x & 7) << 12) + ((blockIdx.x >> 3) << 7);
    const int gn = blockIdx.y * 128;
    const int wr = (wid >> 1) * 64;
    const int wc = (wid & 1) * 64;
    const int l15 = lane & 15;
    const int lk  = (lane >> 4) * 8;
    const int rl  = lane >> 3;
    const int ch  = (lane & 7) ^ rl;

    f32x4 acc[4][4];
    #pragma unroll
    for (int m = 0; m < 4; ++m)
        #pragma unroll
        for (int n = 0; n < 4; ++n)
            #pragma unroll
            for (int r = 0; r < 4; ++r) acc[m][n][r] = 0.f;

    for (int k0 = 0; k0 < 256; k0 += 64) {
        #pragma unroll
        for (int it = 0; it < 4; ++it) {
            const int br = it * 32 + wid * 8;
            gload16(&Bt[(size_t)(gn + br + rl) * 256 + k0 + ch * 8], &Bs[br][0]);
            gload16(&Ap[(size_t)(gm + br + rl) * 256 + k0 + ch * 8], &As[br][0]);
        }
        __syncthreads();

        #pragma unroll
        for (int kk = 0; kk < 64; kk += 32) {
            bf16x8 a[4], b[4];
            #pragma unroll
            for (int m = 0; m < 4; ++m) {
                const int r = wr + m * 16 + l15;
                a[m] = *(const bf16x8*)&As[r][SWZ(r, kk + lk)];
            }
            #pragma unroll
            for (int n = 0; n < 4; ++n) {
                const int r = wc + n * 16 + l15;
                b[n] = *(const bf16x8*)&Bs[r][SWZ(r, kk + lk)];
            }
            #pragma unroll
            for (int m = 0; m < 4; ++m)
                #pragma unroll
                for (int n = 0; n < 4; ++n)
                    acc[m][n] = __builtin_amdgcn_mfma_f32_16x16x32_bf16(a[m], b[n], acc[m][n], 0, 0, 0);
        }
        __syncthreads();
    }

    const int cr = (lane >> 4) * 4;
    #pragma unroll
    for (int n = 0; n < 4; ++n) {
        const int col = gn + wc + n * 16 + l15;
        const float bv = bias[col];
        #pragma unroll
        for (int m = 0; m < 4; ++m)
            #pragma unroll
            for (int r = 0; r < 4; ++r) {
                const int row = gm + wr + m * 16 + cr + r;
                C[(size_t)row * 256 + col] = acc[m][n][r] + bv;
            }
    }
}

// ---------------------------------------------------------------------------
// Sampling: block = 8 queries (XCD-pinned batch). Phase 1: 256 threads
// (8 queries x 32 (h,p)) compute softmax/tanh corner weights + packed coords.
// Phase 2: 2 passes, 64 lanes per query, uint2 gathers (4 bf16 ch/lane).
// ---------------------------------------------------------------------------
__global__ __launch_bounds__(256)
void sample_gather_kernel(const unsigned short* __restrict__ projv, // [B][4096][256] bf16
                          const float* __restrict__ lin,            // [M][96]
                          const float* __restrict__ refp,           // [M][2]
                          unsigned short* __restrict__ sampled)     // [M][256] bf16
{
    __shared__ float4 s_w[8][32];
    __shared__ unsigned s_xy[8][32];

    const int i = blockIdx.x;
    const int b = i & 7;                          // batch == XCD
    const int bn0 = (b << 12) + ((i >> 3) << 3);  // first of 8 queries
    const int t = threadIdx.x;

    {
        const int sub = t >> 5;        // 0..7
        const int q = t & 31;          // h*4 + p
        const int h = q >> 2;
        const int p = q & 3;
        const int bn = bn0 + sub;
        const float2 rp = *(const float2*)&refp[(size_t)bn * 2];
        const float2 ol = *(const float2*)&lin[(size_t)bn * 96 + h * 8 + p * 2];
        const float al  = lin[(size_t)bn * 96 + 64 + q];

        float mx = al;
        mx = fmaxf(mx, __shfl_xor(mx, 1));
        mx = fmaxf(mx, __shfl_xor(mx, 2));
        float e = expf(al - mx);
        float s = e;
        s += __shfl_xor(s, 1);
        s += __shfl_xor(s, 2);
        const float aw = e / s;

        const float lx = fminf(fmaxf(rp.x + tanhf(ol.x) * 0.5f, 0.f), 1.f);
        const float ly = fminf(fmaxf(rp.y + tanhf(ol.y) * 0.5f, 0.f), 1.f);
        const float x = lx * (float)IMG - 0.5f;
        const float y = ly * (float)IMG - 0.5f;
        const float x0f = floorf(x), y0f = floorf(y);
        const int x0 = (int)x0f, y0 = (int)y0f;
        const float wx1 = x - x0f, wx0 = 1.f - wx1;
        const float wy1 = y - y0f, wy0 = 1.f - wy1;
        const bool vx0 = (x0 >= 0), vx1 = (x0 + 1 < IMG);
        const bool vy0 = (y0 >= 0), vy1 = (y0 + 1 < IMG);
        float4 w;
        w.x = (vx0 && vy0) ? wx0 * wy0 * aw : 0.f;
        w.y = (vx1 && vy0) ? wx1 * wy0 * aw : 0.f;
        w.z = (vx0 && vy1) ? wx0 * wy1 * aw : 0.f;
        w.w = (vx1 && vy1) ? wx1 * wy1 * aw : 0.f;
        const int x0c = min(max(x0, 0), IMG - 1), x1c = min(max(x0 + 1, 0), IMG - 1);
        const int y0c = min(max(y0, 0), IMG - 1), y1c = min(max(y0 + 1, 0), IMG - 1);
        s_w[sub][q] = w;
        s_xy[sub][q] = (unsigned)x0c | ((unsigned)x1c << 8) | ((unsigned)y0c << 16) | ((unsigned)y1c << 24);
    }
    __syncthreads();

    const int l = t & 63;
    const int h2 = l >> 3;
    const int cp = l & 7;
    const unsigned short* vbase = projv + ((size_t)b << 20) + h2 * HDIM + cp * 4;

    #pragma unroll
    for (int pass = 0; pass < 2; ++pass) {
        const int sub = (t >> 6) + pass * 4;
        const int bn = bn0 + sub;

        float a0 = 0.f, a1 = 0.f, a2 = 0.f, a3 = 0.f;
        #pragma unroll
        for (int p = 0; p < 4; ++p) {
            const float4 w = s_w[sub][h2 * 4 + p];
            const unsigned xy = s_xy[sub][h2 * 4 + p];
            const int x0 = xy & 255, x1 = (xy >> 8) & 255;
            const int y0 = (xy >> 16) & 255, y1 = xy >> 24;
            const uint2 u00 = *(const uint2*)&vbase[(((y0 << 6) + x0) << 8)];
            const uint2 u01 = *(const uint2*)&vbase[(((y0 << 6) + x1) << 8)];
            const uint2 u10 = *(const uint2*)&vbase[(((y1 << 6) + x0) << 8)];
            const uint2 u11 = *(const uint2*)&vbase[(((y1 << 6) + x1) << 8)];
            a0 += w.x * b2f((unsigned short)(u00.x & 0xffff)) + w.y * b2f((unsigned short)(u01.x & 0xffff))
                + w.z * b2f((unsigned short)(u10.x & 0xffff)) + w.w * b2f((unsigned short)(u11.x & 0xffff));
            a1 += w.x * b2f((unsigned short)(u00.x >> 16)) + w.y * b2f((unsigned short)(u01.x >> 16))
                + w.z * b2f((unsigned short)(u10.x >> 16)) + w.w * b2f((unsigned short)(u11.x >> 16));
            a2 += w.x * b2f((unsigned short)(u00.y & 0xffff)) + w.y * b2f((unsigned short)(u01.y & 0xffff))
                + w.z * b2f((unsigned short)(u10.y & 0xffff)) + w.w * b2f((unsigned short)(u11.y & 0xffff));
            a3 += w.x * b2f((unsigned short)(u00.y >> 16)) + w.y * b2f((unsigned short)(u01.y >> 16))
                + w.z * b2f((unsigned short)(u10.y >> 16)) + w.w * b2f((unsigned short)(u11.y >> 16));
        }
        uint2 outp;
        outp.x = (unsigned)f2b(a0) | ((unsigned)f2b(a1) << 16);
        outp.y = (unsigned)f2b(a2) | ((unsigned)f2b(a3) << 16);
        *(uint2*)&sampled[(size_t)bn * 256 + h2 * HDIM + cp * 4] = outp;
    }
}

// ---------------------------------------------------------------------------
extern "C" void kernel_launch(void* const* d_in, const int* in_sizes, int n_in,
                              void* d_out, int out_size, void* d_ws, size_t ws_size,
                              hipStream_t stream)
{
    const float* query  = (const float*)d_in[0];
    const float* value  = (const float*)d_in[1];
    const float* refp   = (const float*)d_in[2];
    const float* W_off  = (const float*)d_in[3];
    const float* b_off  = (const float*)d_in[4];
    const float* W_attn = (const float*)d_in[5];
    const float* b_attn = (const float*)d_in[6];
    const float* W_val  = (const float*)d_in[7];
    const float* b_val  = (const float*)d_in[8];
    const float* W_out  = (const float*)d_in[9];
    const float* b_out  = (const float*)d_in[10];
    float* out = (float*)d_out;

    // workspace layout
    char* ws = (char*)d_ws;
    unsigned short* projv    = (unsigned short*)ws; ws += (size_t)MTOT * 256 * 2;
    unsigned short* sampled  = (unsigned short*)ws; ws += (size_t)MTOT * 256 * 2;
    unsigned short* value_bf = (unsigned short*)ws; ws += (size_t)MTOT * 256 * 2;
    float*          lin      = (float*)ws;          ws += (size_t)MTOT * 96 * 4;
    unsigned short* Wv_t     = (unsigned short*)ws; ws += 256 * 256 * 2;
    unsigned short* Wo_t     = (unsigned short*)ws; ws += 256 * 256 * 2;
    unsigned short* Wl_h     = (unsigned short*)ws; ws += 128 * 256 * 2;
    unsigned short* Wl_l     = (unsigned short*)ws; ws += 128 * 256 * 2;
    float*          bias_lin = (float*)ws;          ws += 128 * 4;

    dim3 blk(256);

    // 1) weight prep + value f32->bf16
    cvt_weights_kernel<<<dim3(256), blk, 0, stream>>>(W_val, W_out, W_off, W_attn, b_off, b_attn,
                                                      Wv_t, Wo_t, Wl_h, Wl_l, bias_lin);
    cvt_value_kernel<<<dim3(2048), blk, 0, stream>>>(value, value_bf);

    // 2) offset/attn logits (blocks 0..255) + value projection (256..767)
    fused_gemms_kernel<<<dim3(768), blk, 0, stream>>>(value_bf, query, Wv_t, Wl_h, Wl_l,
                                                      b_val, bias_lin, projv, lin);

    // 3) sampling/gather (XCD-pinned batch -> L2-resident projv & lin)
    sample_gather_kernel<<<dim3(MTOT / 8), blk, 0, stream>>>(projv, lin, refp, sampled);

    // 4) output projection: out = sampled @ W_out + b_out -> f32
    gemm_out_kernel<<<dim3(MTOT / 128, 2), blk, 0, stream>>>(sampled, Wo_t, b_out, out);
}